// Round 2
// baseline (708.860 us; speedup 1.0000x reference)
//
#include <hip/hip_runtime.h>
#include <math.h>

constexpr int TOKENS = 16384;
constexpr int DIM    = 4096;
constexpr int NE     = 64;   // experts
constexpr int TOPK   = 8;

constexpr int TM   = 32;  // tokens per block
constexpr int KB   = 32;  // k-chunk staged per iteration
constexpr int XPAD = 36;  // doubles per xs row (32 + 4 pad, keeps 16B align)
constexpr int WPAD = 68;  // doubles per ws row (64 + 4 pad, keeps 32B align)

__global__ __launch_bounds__(256, 2)
void router_kernel(const float* __restrict__ x,
                   const float* __restrict__ W,
                   float* __restrict__ out)
{
    __shared__ double xs[KB][XPAD];     // x tile, transposed, fp64: xs[k][token]
    __shared__ double ws[KB][WPAD];     // W tile, transposed, fp64: ws[k][expert]
    __shared__ double ls[TM][NE + 1];   // fp64 logits for this block's tokens

    const int t    = threadIdx.x;
    const int tx   = t & 15;   // expert group: experts 4*tx .. 4*tx+3
    const int ty   = t >> 4;   // token group:  tokens  2*ty .. 2*ty+1
    const int tok0 = blockIdx.x * TM;

    double acc[2][4];
#pragma unroll
    for (int i = 0; i < 2; ++i)
#pragma unroll
        for (int j = 0; j < 4; ++j) acc[i][j] = 0.0;

    for (int k0 = 0; k0 < DIM; k0 += KB) {
        // stage x tile: TM*KB = 1024 elems, 4 per thread, coalesced rows; cvt to fp64
#pragma unroll
        for (int i = 0; i < (TM * KB) / 256; ++i) {
            int idx = t + 256 * i;
            int tok = idx >> 5;          // / KB
            int kk  = idx & (KB - 1);
            xs[kk][tok] = (double)x[(size_t)(tok0 + tok) * DIM + k0 + kk];
        }
        // stage W tile: NE*KB = 2048 elems, 8 per thread; cvt to fp64
#pragma unroll
        for (int i = 0; i < (NE * KB) / 256; ++i) {
            int idx = t + 256 * i;
            int e   = idx >> 5;
            int kk  = idx & (KB - 1);
            ws[kk][e] = (double)W[(size_t)e * DIM + k0 + kk];
        }
        __syncthreads();

#pragma unroll
        for (int kk = 0; kk < KB; ++kk) {
            double2 xv = *(const double2*)&xs[kk][2 * ty];
            double4 wv = *(const double4*)&ws[kk][4 * tx];
            acc[0][0] = fma(xv.x, wv.x, acc[0][0]);
            acc[0][1] = fma(xv.x, wv.y, acc[0][1]);
            acc[0][2] = fma(xv.x, wv.z, acc[0][2]);
            acc[0][3] = fma(xv.x, wv.w, acc[0][3]);
            acc[1][0] = fma(xv.y, wv.x, acc[1][0]);
            acc[1][1] = fma(xv.y, wv.y, acc[1][1]);
            acc[1][2] = fma(xv.y, wv.z, acc[1][2]);
            acc[1][3] = fma(xv.y, wv.w, acc[1][3]);
        }
        __syncthreads();
    }

    // dump fp64 logits to LDS
#pragma unroll
    for (int i = 0; i < 2; ++i)
#pragma unroll
        for (int j = 0; j < 4; ++j)
            ls[2 * ty + i][4 * tx + j] = acc[i][j];
    __syncthreads();

    // top-8 on fp64 logits + fp32 softmax: one thread per token (threads 0..TM-1)
    if (t < TM) {
        const int tok = tok0 + t;
        double pv[TOPK];
        int    pi[TOPK];
#pragma unroll
        for (int j = 0; j < TOPK; ++j) {
            double best = -1e300;
            int    bi   = 0;
            // ascending scan, strict '>' => lowest index wins ties (lax.top_k)
            for (int e = 0; e < NE; ++e) {
                double v = ls[t][e];
                if (v > best) { best = v; bi = e; }
            }
            pv[j] = best;
            pi[j] = bi;
            ls[t][bi] = -1e300;
        }
        // softmax over the 8 in fp32 (mirrors top_k_values.astype(float32))
        float pf[TOPK];
#pragma unroll
        for (int j = 0; j < TOPK; ++j) pf[j] = (float)pv[j];
        float m = pf[0];   // values sorted descending
        float ex[TOPK];
        float s = 0.f;
#pragma unroll
        for (int j = 0; j < TOPK; ++j) { ex[j] = expf(pf[j] - m); s += ex[j]; }
        float inv = 1.f / s;
#pragma unroll
        for (int j = 0; j < TOPK; ++j) {
            out[(size_t)tok * TOPK + j] = ex[j] * inv;                          // scores
            out[(size_t)TOKENS * TOPK + (size_t)tok * TOPK + j] = (float)pi[j]; // indices
        }
    }
}

extern "C" void kernel_launch(void* const* d_in, const int* in_sizes, int n_in,
                              void* d_out, int out_size, void* d_ws, size_t ws_size,
                              hipStream_t stream)
{
    const float* x = (const float*)d_in[0];
    const float* W = (const float*)d_in[1];
    float* out = (float*)d_out;

    dim3 grid(TOKENS / TM);
    dim3 block(256);
    hipLaunchKernelGGL(router_kernel, grid, block, 0, stream, x, W, out);
}

// Round 3
// 543.306 us; speedup vs baseline: 1.3047x; 1.3047x over previous
//
#include <hip/hip_runtime.h>
#include <math.h>

constexpr int TOKENS = 16384;
constexpr int DIM    = 4096;
constexpr int NE     = 64;   // experts
constexpr int TOPK   = 8;

constexpr int TM  = 64;   // tokens per block
constexpr int KB  = 64;   // k-chunk staged per iteration
constexpr int ST  = 68;   // LDS row stride in floats (odd multiple of 16B -> aligned + bank-rotated)

// block = 512 threads (8 waves): 256 compute-threads x 2 K-halves.
// grid = 256 blocks = 1 block/CU, 2 waves/SIMD.
__global__ __launch_bounds__(512, 2)
void router_kernel(const float* __restrict__ x,
                   const float* __restrict__ W,
                   float* __restrict__ out)
{
    // xs[64][ST] fp32, ws[64][ST] fp32; later aliased as ls[64][65] fp64 logits
    __shared__ __align__(16) char smem_raw[2 * TM * ST * 4];
    float*  xs = (float*)smem_raw;
    float*  ws = xs + TM * ST;
    double* ls = (double*)smem_raw;           // [64][65] = 33280 B <= 34816 B

    const int t    = threadIdx.x;
    const int t2   = t & 255;                 // compute id within K-half
    const int kh   = t >> 8;                  // K-half: 0 or 1
    const int ty   = t2 & 15;                 // token group: tokens ty + 16*i
    const int tx   = t2 >> 4;                 // expert group: experts tx + 16*j
    const int tok0 = blockIdx.x * TM;
    const int kbase = kh * (KB / 2);          // this half's k-offset within staged tile

    // staging coordinates (2 float4 of x and of W per thread per iter)
    const int row0 = t >> 4;                  // 0..31
    const int row1 = (t + 512) >> 4;          // 32..63
    const int c4   = (t & 15) * 4;            // float offset within row

    int xoff[4], woff[4];
#pragma unroll
    for (int i = 0; i < 4; ++i) xoff[i] = (ty + 16 * i) * ST;
#pragma unroll
    for (int j = 0; j < 4; ++j) woff[j] = (tx + 16 * j) * ST;

    double acc[4][4];
#pragma unroll
    for (int i = 0; i < 4; ++i)
#pragma unroll
        for (int j = 0; j < 4; ++j) acc[i][j] = 0.0;

    for (int k0 = 0; k0 < DIM; k0 += KB) {
        // ---- stage x tile and W tile (row-major, stride ST) ----
        {
            float4 xv0 = *(const float4*)&x[(size_t)(tok0 + row0) * DIM + k0 + c4];
            float4 xv1 = *(const float4*)&x[(size_t)(tok0 + row1) * DIM + k0 + c4];
            float4 wv0 = *(const float4*)&W[(size_t)row0 * DIM + k0 + c4];
            float4 wv1 = *(const float4*)&W[(size_t)row1 * DIM + k0 + c4];
            *(float4*)&xs[row0 * ST + c4] = xv0;
            *(float4*)&xs[row1 * ST + c4] = xv1;
            *(float4*)&ws[row0 * ST + c4] = wv0;
            *(float4*)&ws[row1 * ST + c4] = wv1;
        }
        __syncthreads();

        // ---- compute this K-half: 8 chunks of 4 k ----
#pragma unroll
        for (int c = 0; c < 8; ++c) {
            const int kk = kbase + c * 4;
            float4 xr[4], wr[4];
#pragma unroll
            for (int i = 0; i < 4; ++i) xr[i] = *(const float4*)&xs[xoff[i] + kk];
#pragma unroll
            for (int j = 0; j < 4; ++j) wr[j] = *(const float4*)&ws[woff[j] + kk];
#pragma unroll
            for (int q = 0; q < 4; ++q) {
                double xd[4], wd[4];
#pragma unroll
                for (int i = 0; i < 4; ++i) xd[i] = (double)((const float*)&xr[i])[q];
#pragma unroll
                for (int j = 0; j < 4; ++j) wd[j] = (double)((const float*)&wr[j])[q];
#pragma unroll
                for (int i = 0; i < 4; ++i)
#pragma unroll
                    for (int j = 0; j < 4; ++j)
                        acc[i][j] = fma(xd[i], wd[j], acc[i][j]);
            }
        }
        __syncthreads();
    }

    // ---- combine K-halves into fp64 logits in LDS (deterministic order) ----
    if (kh == 0) {
#pragma unroll
        for (int i = 0; i < 4; ++i)
#pragma unroll
            for (int j = 0; j < 4; ++j)
                ls[(ty + 16 * i) * 65 + (tx + 16 * j)] = acc[i][j];
    }
    __syncthreads();
    if (kh == 1) {
#pragma unroll
        for (int i = 0; i < 4; ++i)
#pragma unroll
            for (int j = 0; j < 4; ++j)
                ls[(ty + 16 * i) * 65 + (tx + 16 * j)] += acc[i][j];
    }
    __syncthreads();

    // ---- top-8 + fp32 softmax: threads 0..63, one token each ----
    if (t < TM) {
        const int tok = tok0 + t;
        double pv[TOPK];
        int    pi[TOPK];
#pragma unroll
        for (int j = 0; j < TOPK; ++j) {
            double best = -1e300;
            int    bi   = 0;
            // ascending scan, strict '>' => lowest index wins ties (lax.top_k)
            for (int e = 0; e < NE; ++e) {
                double v = ls[t * 65 + e];
                if (v > best) { best = v; bi = e; }
            }
            pv[j] = best;
            pi[j] = bi;
            ls[t * 65 + bi] = -1e300;
        }
        float pf[TOPK];
#pragma unroll
        for (int j = 0; j < TOPK; ++j) pf[j] = (float)pv[j];
        float m = pf[0];   // descending order => pf[0] is max
        float ex[TOPK];
        float s = 0.f;
#pragma unroll
        for (int j = 0; j < TOPK; ++j) { ex[j] = expf(pf[j] - m); s += ex[j]; }
        float inv = 1.f / s;
#pragma unroll
        for (int j = 0; j < TOPK; ++j) {
            out[(size_t)tok * TOPK + j] = ex[j] * inv;                          // scores
            out[(size_t)TOKENS * TOPK + (size_t)tok * TOPK + j] = (float)pi[j]; // indices
        }
    }
}

extern "C" void kernel_launch(void* const* d_in, const int* in_sizes, int n_in,
                              void* d_out, int out_size, void* d_ws, size_t ws_size,
                              hipStream_t stream)
{
    const float* x = (const float*)d_in[0];
    const float* W = (const float*)d_in[1];
    float* out = (float*)d_out;

    dim3 grid(TOKENS / TM);   // 256
    dim3 block(512);
    hipLaunchKernelGGL(router_kernel, grid, block, 0, stream, x, W, out);
}

// Round 5
// 487.069 us; speedup vs baseline: 1.4554x; 1.1155x over previous
//
#include <hip/hip_runtime.h>
#include <math.h>

typedef float  f32x4 __attribute__((ext_vector_type(4)));
typedef short  s16x8 __attribute__((ext_vector_type(8)));
typedef unsigned short u16x8 __attribute__((ext_vector_type(8)));

constexpr int TOKENS  = 16384;
constexpr int DIM     = 4096;
constexpr int NE      = 64;
constexpr int TOPK    = 8;
constexpr int TM      = 64;      // tokens per block
constexpr int KB      = 32;      // k per staged tile
constexpr int NIT     = DIM / KB;
constexpr int LISTCAP = 16384;
constexpr float GAPTH = 1e-4f;   // flag threshold (max phase-1 err ~2e-5)

__device__ __forceinline__ unsigned short bf_rne(float f) {
    unsigned u = __float_as_uint(f);
    u += 0x7FFFu + ((u >> 16) & 1u);
    return (unsigned short)(u >> 16);
}
__device__ __forceinline__ float bf_f32(unsigned short h) {
    return __uint_as_float(((unsigned)h) << 16);
}

__global__ void zero_cnt_kernel(int* wsI) { if (threadIdx.x == 0) wsI[0] = 0; }

// grid 256, block 256 (4 waves). Each wave: 16 tokens x 64 experts (4 tiles of 16x16).
__global__ __launch_bounds__(256)
void gemm_topk_kernel(const float* __restrict__ x, const float* __restrict__ W,
                      float* __restrict__ out, int* __restrict__ wsI)
{
    // packed MFMA fragments, XOR-swizzled (conflict-free reads AND writes):
    // segments: XH 0, XL 2048, WH 4096, WL 6144 (ushorts)
    __shared__ __align__(16) unsigned short frag[8192];
    __shared__ float ls[TM][NE + 4];

    const int t    = threadIdx.x;
    const int tok0 = blockIdx.x * TM;

    // ---- staging coords: thread -> (row 0..63, q = k/8), 8 consecutive k ----
    const int srow = t >> 2;
    const int sq   = t & 3;
    const int sn   = srow & 15;
    const int sT   = srow >> 4;
    const int sdst = sT * 512 + (16 * sq + (sn ^ (2 * sq))) * 8;
    const float* xg = x + (size_t)(tok0 + srow) * DIM + 8 * sq;
    const float* wg = W + (size_t)srow * DIM + 8 * sq;

    // ---- compute coords: wave w = token group; lane fragment offset ----
    const int w  = t >> 6;
    const int l  = t & 63;
    const int lq = l >> 4;
    const int ln = l & 15;
    const int fo = (16 * lq + (ln ^ (2 * lq))) * 8;

    f32x4 acc[4];
#pragma unroll
    for (int T = 0; T < 4; ++T) acc[T] = (f32x4){0.f, 0.f, 0.f, 0.f};

    float4 xa = *(const float4*)xg;
    float4 xb = *(const float4*)(xg + 4);
    float4 wa = *(const float4*)wg;
    float4 wb = *(const float4*)(wg + 4);

    for (int it = 0; it < NIT; ++it) {
        __syncthreads();   // previous iter's MFMA reads done
        {
            float vx[8] = {xa.x, xa.y, xa.z, xa.w, xb.x, xb.y, xb.z, xb.w};
            float vw[8] = {wa.x, wa.y, wa.z, wa.w, wb.x, wb.y, wb.z, wb.w};
            u16x8 vxh, vxl, vwh, vwl;
#pragma unroll
            for (int j = 0; j < 8; ++j) {
                unsigned short h1 = bf_rne(vx[j]);
                vxh[j] = h1;
                vxl[j] = bf_rne(vx[j] - bf_f32(h1));
                unsigned short h2 = bf_rne(vw[j]);
                vwh[j] = h2;
                vwl[j] = bf_rne(vw[j] - bf_f32(h2));
            }
            *(u16x8*)&frag[   0 + sdst] = vxh;
            *(u16x8*)&frag[2048 + sdst] = vxl;
            *(u16x8*)&frag[4096 + sdst] = vwh;
            *(u16x8*)&frag[6144 + sdst] = vwl;
        }
        __syncthreads();
        if (it + 1 < NIT) {   // prefetch next k-chunk; drains during MFMA phase
            const float* xp = xg + (size_t)(it + 1) * KB;
            const float* wp = wg + (size_t)(it + 1) * KB;
            xa = *(const float4*)xp;  xb = *(const float4*)(xp + 4);
            wa = *(const float4*)wp;  wb = *(const float4*)(wp + 4);
        }
        // ---- MFMA: A = tokens (this wave's group), B = 4 expert tiles ----
        s16x8 ah = *(const s16x8*)&frag[   0 + w * 512 + fo];
        s16x8 al = *(const s16x8*)&frag[2048 + w * 512 + fo];
#pragma unroll
        for (int T = 0; T < 4; ++T) {
            s16x8 bh = *(const s16x8*)&frag[4096 + T * 512 + fo];
            s16x8 bl = *(const s16x8*)&frag[6144 + T * 512 + fo];
            acc[T] = __builtin_amdgcn_mfma_f32_16x16x32_bf16(ah, bh, acc[T], 0, 0, 0);
            acc[T] = __builtin_amdgcn_mfma_f32_16x16x32_bf16(ah, bl, acc[T], 0, 0, 0);
            acc[T] = __builtin_amdgcn_mfma_f32_16x16x32_bf16(al, bh, acc[T], 0, 0, 0);
        }
    }

    __syncthreads();
    // D layout (m89-verified): col = l&15, row = (l>>4)*4 + r
#pragma unroll
    for (int T = 0; T < 4; ++T)
#pragma unroll
        for (int r = 0; r < 4; ++r)
            ls[16 * w + 4 * lq + r][16 * T + ln] = acc[T][r];
    __syncthreads();

    // ---- top-9 scan + gap flag + fp32 softmax: one thread per token ----
    if (t < TM) {
        const int tok = tok0 + t;
        float v[9]; int idx[9];
#pragma unroll
        for (int j = 0; j < 9; ++j) {
            float best = -3.4e38f; int bi = 0;
            for (int e = 0; e < NE; ++e) {
                float q = ls[t][e];
                if (q > best) { best = q; bi = e; }   // lowest index wins ties
            }
            v[j] = best; idx[j] = bi;
            ls[t][bi] = -3.4e38f;
        }
        bool flag = false;
#pragma unroll
        for (int j = 0; j < 8; ++j)
            if (v[j] - v[j + 1] < GAPTH) flag = true;

        float m = v[0], s = 0.f, ex[8];
#pragma unroll
        for (int j = 0; j < 8; ++j) { ex[j] = expf(v[j] - m); s += ex[j]; }
        float inv = 1.f / s;
#pragma unroll
        for (int j = 0; j < 8; ++j) {
            out[(size_t)tok * TOPK + j] = ex[j] * inv;
            out[(size_t)TOKENS * TOPK + (size_t)tok * TOPK + j] = (float)idx[j];
        }
        if (flag) {
            int pos = atomicAdd(wsI, 1);
            if (pos < LISTCAP) wsI[16 + pos] = tok;
        }
    }
}

// exact fp64 recompute for flagged tokens (no MFMA-layout risk)
__global__ __launch_bounds__(256)
void refine_kernel(const float* __restrict__ x, const float* __restrict__ W,
                   float* __restrict__ out, const int* __restrict__ wsI)
{
    __shared__ float  xr[DIM];     // 16 KB
    __shared__ double pt[256];
    __shared__ double lg[NE];

    int cnt = wsI[0];
    if (cnt > LISTCAP) cnt = LISTCAP;
    const int t = threadIdx.x;

    for (int g = blockIdx.x; g < cnt; g += gridDim.x) {
        const int tok = wsI[16 + g];
        __syncthreads();   // previous iteration fully done before restaging
        for (int i = t; i < DIM / 4; i += 256)
            *(float4*)&xr[4 * i] = *(const float4*)&x[(size_t)tok * DIM + 4 * i];
        __syncthreads();

        const int e  = t & 63;
        const int ks = t >> 6;
        const float* wp = W + (size_t)e * DIM + ks * 1024;
        const float* xp = xr + ks * 1024;
        double p = 0.0;
        for (int i = 0; i < 256; ++i) {
            float4 wv = *(const float4*)&wp[4 * i];
            float4 xv = *(const float4*)&xp[4 * i];
            p = fma((double)xv.x, (double)wv.x, p);
            p = fma((double)xv.y, (double)wv.y, p);
            p = fma((double)xv.z, (double)wv.z, p);
            p = fma((double)xv.w, (double)wv.w, p);
        }
        pt[t] = p;
        __syncthreads();
        if (t < NE)
            lg[t] = ((pt[t] + pt[t + 64]) + pt[t + 128]) + pt[t + 192];  // fixed order
        __syncthreads();
        if (t == 0) {
            double vv[8]; int ii[8];
#pragma unroll
            for (int j = 0; j < 8; ++j) {
                double best = -1e300; int bi = 0;
                for (int e2 = 0; e2 < NE; ++e2) {
                    double q = lg[e2];
                    if (q > best) { best = q; bi = e2; }
                }
                vv[j] = best; ii[j] = bi;
                lg[bi] = -1e300;
            }
            float pf[8], ex[8], s = 0.f;
#pragma unroll
            for (int j = 0; j < 8; ++j) pf[j] = (float)vv[j];
            float m = pf[0];
#pragma unroll
            for (int j = 0; j < 8; ++j) { ex[j] = expf(pf[j] - m); s += ex[j]; }
            float inv = 1.f / s;
#pragma unroll
            for (int j = 0; j < 8; ++j) {
                out[(size_t)tok * TOPK + j] = ex[j] * inv;
                out[(size_t)TOKENS * TOPK + (size_t)tok * TOPK + j] = (float)ii[j];
            }
        }
    }
}

extern "C" void kernel_launch(void* const* d_in, const int* in_sizes, int n_in,
                              void* d_out, int out_size, void* d_ws, size_t ws_size,
                              hipStream_t stream)
{
    const float* x = (const float*)d_in[0];
    const float* W = (const float*)d_in[1];
    float* out = (float*)d_out;
    int* wsI = (int*)d_ws;

    hipLaunchKernelGGL(zero_cnt_kernel, dim3(1), dim3(64), 0, stream, wsI);
    hipLaunchKernelGGL(gemm_topk_kernel, dim3(TOKENS / TM), dim3(256), 0, stream, x, W, out, wsI);
    hipLaunchKernelGGL(refine_kernel, dim3(256), dim3(256), 0, stream, x, W, out, wsI);
}